// Round 2
// baseline (339.749 us; speedup 1.0000x reference)
//
#include <hip/hip_runtime.h>

#define TOK    18464      // 32*577 tokens
#define SEQ    577
#define EMB    768
#define NH     12
#define HD     64
#define BHn    384        // 32*12
#define HEADSZ 36928      // SEQ*HD
#define PLANE  14180352   // TOK*768
#define SPAD   640        // padded seq stride for V^T

typedef float f32x4 __attribute__((ext_vector_type(4)));
typedef short s16x8 __attribute__((ext_vector_type(8)));

__device__ __forceinline__ unsigned short f2bf(float f) {
  unsigned u = __builtin_bit_cast(unsigned, f);
  return (unsigned short)((u + 0x7fffu + ((u >> 16) & 1u)) >> 16);
}

__device__ __forceinline__ void gload16(const void* g, void* l) {
  __builtin_amdgcn_global_load_lds(
      (const __attribute__((address_space(1))) void*)g,
      (__attribute__((address_space(3))) void*)l, 16, 0, 0);
}

// ---------------- fp32 -> bf16 conversion (x) ----------------
__global__ void cvt_x(const float* __restrict__ src, short* __restrict__ dst, int n8) {
  int i = blockIdx.x * blockDim.x + threadIdx.x;
  if (i >= n8) return;
  const float4* s4 = reinterpret_cast<const float4*>(src + (size_t)i * 8);
  float4 a = s4[0], b = s4[1];
  s16x8 o;
  o[0] = (short)f2bf(a.x); o[1] = (short)f2bf(a.y);
  o[2] = (short)f2bf(a.z); o[3] = (short)f2bf(a.w);
  o[4] = (short)f2bf(b.x); o[5] = (short)f2bf(b.y);
  o[6] = (short)f2bf(b.z); o[7] = (short)f2bf(b.w);
  *reinterpret_cast<s16x8*>(dst + (size_t)i * 8) = o;
}

// ---------------- weight conversion ----------------
__global__ void cvt_w(const float* __restrict__ wq, const float* __restrict__ wk,
                      const float* __restrict__ wv, const float* __restrict__ wp,
                      short* __restrict__ wqkv, short* __restrict__ wpb) {
  int tid = blockIdx.x * blockDim.x + threadIdx.x;
  if (tid >= 294912) return;
  int region = tid / 73728;
  int off = (tid % 73728) * 8;
  const float* s; short* d;
  if (region == 0)      { s = wq + off; d = wqkv + off; }
  else if (region == 1) { s = wk + off; d = wqkv + 589824 + off; }
  else if (region == 2) { s = wv + off; d = wqkv + 2 * 589824 + off; }
  else                  { s = wp + off; d = wpb + off; }
  const float4* s4 = reinterpret_cast<const float4*>(s);
  float4 a = s4[0], b = s4[1];
  s16x8 o;
  o[0] = (short)f2bf(a.x); o[1] = (short)f2bf(a.y);
  o[2] = (short)f2bf(a.z); o[3] = (short)f2bf(a.w);
  o[4] = (short)f2bf(b.x); o[5] = (short)f2bf(b.y);
  o[6] = (short)f2bf(b.z); o[7] = (short)f2bf(b.w);
  *reinterpret_cast<s16x8*>(d) = o;
}

// ---------------- 128x128 bf16 GEMM, B^T layout ----------------
// MODE 0: C -> Q,K planes [B][H][S][D] bf16 + V transposed [B][H][D][SPAD] bf16
// MODE 1: C + bias -> fp32 out
template <int MODE>
__launch_bounds__(256)
__global__ void gemm_bt(const short* __restrict__ A, const short* __restrict__ Bw,
                        short* __restrict__ qk_out, short* __restrict__ vt_out,
                        float* __restrict__ out, const float* __restrict__ bias,
                        int M, int nnt) {
  __shared__ short As[128 * 32];
  __shared__ short Bs[128 * 32];
  // bijective XCD swizzle (m204)
  int bid = blockIdx.x, nwg = gridDim.x;
  int qq = nwg >> 3, rr = nwg & 7;
  int xcd = bid & 7, loc = bid >> 3;
  int wgid = (xcd < rr ? xcd * (qq + 1) : rr * (qq + 1) + (xcd - rr) * qq) + loc;
  int tn = wgid % nnt;
  int tm = wgid / nnt;
  int tid = threadIdx.x;
  int w = tid >> 6, lane = tid & 63;
  int wm = w >> 1, wn = w & 1;
  int lr = lane & 15, lg = lane >> 4;
  int m0 = tm * 128, n0 = tn * 128;

  f32x4 acc[4][4] = {};

  int srow = tid >> 2;
  int scol = (tid & 3) * 8;

  for (int kt = 0; kt < 24; ++kt) {
    int kb = kt * 32;
    __syncthreads();
    #pragma unroll
    for (int it = 0; it < 2; ++it) {
      int row = srow + it * 64;
      int gr = m0 + row; if (gr >= M) gr = M - 1;
      gload16(A + (size_t)gr * EMB + kb + scol, (char*)As + w * 1024 + it * 4096);
      int rb = n0 + row;
      gload16(Bw + (size_t)rb * EMB + kb + scol, (char*)Bs + w * 1024 + it * 4096);
    }
    __syncthreads();
    s16x8 af[4], bfr[4];
    #pragma unroll
    for (int f = 0; f < 4; ++f) {
      af[f]  = *reinterpret_cast<const s16x8*>(&As[(wm * 64 + f * 16 + lr) * 32 + lg * 8]);
      bfr[f] = *reinterpret_cast<const s16x8*>(&Bs[(wn * 64 + f * 16 + lr) * 32 + lg * 8]);
    }
    #pragma unroll
    for (int i = 0; i < 4; ++i)
      #pragma unroll
      for (int j = 0; j < 4; ++j)
        acc[i][j] = __builtin_amdgcn_mfma_f32_16x16x32_bf16(af[i], bfr[j], acc[i][j], 0, 0, 0);
  }

  int mbase = m0 + wm * 64;
  int nbase = n0 + wn * 64;
  #pragma unroll
  for (int i = 0; i < 4; ++i) {
    #pragma unroll
    for (int j = 0; j < 4; ++j) {
      #pragma unroll
      for (int r = 0; r < 4; ++r) {
        int row = mbase + i * 16 + lg * 4 + r;
        int col = nbase + j * 16 + lr;
        if (row < M) {
          float v = acc[i][j][r];
          if (MODE == 0) {
            int b = row / SEQ;
            int s = row - b * SEQ;
            if (col >= 1536) {        // V -> transposed [bh][d][SPAD]
              int rem = col - 1536;
              int h = rem >> 6, d = rem & 63;
              vt_out[((size_t)(b * NH + h) * HD + d) * SPAD + s] = (short)f2bf(v);
            } else {                  // Q,K planes [bh][s][d]
              int which = col >> 9 >> 0;          // 0 for <768? compute below
              which = (col >= 768) ? 1 : 0;
              int rem = col - which * 768;
              int h = rem >> 6, d = rem & 63;
              qk_out[(size_t)which * PLANE + ((size_t)b * NH + h) * HEADSZ + s * HD + d] =
                  (short)f2bf(v);
            }
          } else {
            out[(size_t)row * EMB + col] = v + bias[col];
          }
        }
      }
    }
  }
}

// ---------------- flash attention: 128 q-rows per block, KV tiles of 64 ----------------
__launch_bounds__(256)
__global__ void attn(const short* __restrict__ qkv, const short* __restrict__ vt,
                     short* __restrict__ cat) {
  // XCD swizzle: 1920 blocks, %8==0 -> simple form; keeps one bh's 5 q-tiles on one XCD
  int bid = blockIdx.x;
  int wgid = (bid & 7) * 240 + (bid >> 3);
  int bh = wgid / 5, qt = wgid % 5;
  int b = bh / NH, h = bh % NH;
  const short* Q   = qkv + (size_t)bh * HEADSZ;
  const short* Kp  = qkv + (size_t)PLANE + (size_t)bh * HEADSZ;
  const short* Vtp = vt + (size_t)bh * (HD * SPAD);

  __shared__ short Ks[64 * 72];
  __shared__ short Vs[64 * 72];   // V^T tile: [d][t] padded
  __shared__ short Pl[4][32 * 72];

  int tid = threadIdx.x, w = tid >> 6, lane = tid & 63;
  int lr = lane & 15, lg = lane >> 4;
  int q0 = qt * 128;

  // Q fragments (2 row-blocks of 16 per wave), registers for whole kernel
  s16x8 qf[2][2];
  #pragma unroll
  for (int rb = 0; rb < 2; ++rb) {
    int row = q0 + w * 32 + rb * 16 + lr; if (row >= SEQ) row = SEQ - 1;
    #pragma unroll
    for (int kk = 0; kk < 2; ++kk)
      qf[rb][kk] = *reinterpret_cast<const s16x8*>(&Q[row * HD + kk * 32 + lg * 8]);
  }

  f32x4 acco[2][4] = {};
  float mrow[2][4], lsum[2][4];
  #pragma unroll
  for (int rb = 0; rb < 2; ++rb)
    #pragma unroll
    for (int r = 0; r < 4; ++r) { mrow[rb][r] = -1e30f; lsum[rb][r] = 0.f; }

  int rowk = tid >> 2;            // 0..63
  int colk = (tid & 3) * 16;      // 0,16,32,48

  // stage tile 0
  s16x8 kreg[2], vreg[2];
  #pragma unroll
  for (int p = 0; p < 2; ++p) {
    kreg[p] = *reinterpret_cast<const s16x8*>(&Kp[rowk * HD + colk + p * 8]);
    vreg[p] = *reinterpret_cast<const s16x8*>(&Vtp[rowk * SPAD + colk + p * 8]);
  }
  #pragma unroll
  for (int p = 0; p < 2; ++p) {
    *reinterpret_cast<s16x8*>(&Ks[rowk * 72 + colk + p * 8]) = kreg[p];
    *reinterpret_cast<s16x8*>(&Vs[rowk * 72 + colk + p * 8]) = vreg[p];
  }

  for (int tt = 0; tt < 10; ++tt) {
    int t0 = tt * 64;
    __syncthreads();              // tile tt ready in LDS

    // T14: issue next tile's global loads now; HBM latency hides under compute
    if (tt < 9) {
      int gr = t0 + 64 + rowk; if (gr >= SEQ) gr = SEQ - 1;
      #pragma unroll
      for (int p = 0; p < 2; ++p) {
        kreg[p] = *reinterpret_cast<const s16x8*>(&Kp[gr * HD + colk + p * 8]);
        vreg[p] = *reinterpret_cast<const s16x8*>(&Vtp[rowk * SPAD + t0 + 64 + colk + p * 8]);
      }
    }

    // scores = Q K^T * 0.125
    f32x4 sc[2][4];
    #pragma unroll
    for (int f = 0; f < 4; ++f) {
      s16x8 kf0 = *reinterpret_cast<const s16x8*>(&Ks[(f * 16 + lr) * 72 + lg * 8]);
      s16x8 kf1 = *reinterpret_cast<const s16x8*>(&Ks[(f * 16 + lr) * 72 + 32 + lg * 8]);
      #pragma unroll
      for (int rb = 0; rb < 2; ++rb) {
        f32x4 z = {0.f, 0.f, 0.f, 0.f};
        z = __builtin_amdgcn_mfma_f32_16x16x32_bf16(qf[rb][0], kf0, z, 0, 0, 0);
        sc[rb][f] = __builtin_amdgcn_mfma_f32_16x16x32_bf16(qf[rb][1], kf1, z, 0, 0, 0);
      }
    }
    #pragma unroll
    for (int f = 0; f < 4; ++f) {
      bool valid = (t0 + f * 16 + lr) < SEQ;
      #pragma unroll
      for (int rb = 0; rb < 2; ++rb)
        #pragma unroll
        for (int r = 0; r < 4; ++r)
          sc[rb][f][r] = valid ? sc[rb][f][r] * 0.125f : -1e30f;
    }

    // online softmax per q-row (16 lanes share a row's 64 t-values across f)
    #pragma unroll
    for (int rb = 0; rb < 2; ++rb) {
      #pragma unroll
      for (int r = 0; r < 4; ++r) {
        float mx = fmaxf(fmaxf(sc[rb][0][r], sc[rb][1][r]), fmaxf(sc[rb][2][r], sc[rb][3][r]));
        #pragma unroll
        for (int d = 1; d < 16; d <<= 1) mx = fmaxf(mx, __shfl_xor(mx, d));
        float mn = fmaxf(mrow[rb][r], mx);
        float alpha = __expf(mrow[rb][r] - mn);
        mrow[rb][r] = mn;
        lsum[rb][r] *= alpha;
        #pragma unroll
        for (int f = 0; f < 4; ++f) acco[rb][f][r] *= alpha;
        float ps = 0.f;
        #pragma unroll
        for (int f = 0; f < 4; ++f) {
          float p = __expf(sc[rb][f][r] - mn);
          sc[rb][f][r] = p;
          ps += p;
        }
        #pragma unroll
        for (int d = 1; d < 16; d <<= 1) ps += __shfl_xor(ps, d);
        lsum[rb][r] += ps;
      }
    }

    // P -> per-wave LDS (re-fragment as MFMA A operand)
    #pragma unroll
    for (int rb = 0; rb < 2; ++rb)
      #pragma unroll
      for (int f = 0; f < 4; ++f)
        #pragma unroll
        for (int r = 0; r < 4; ++r)
          Pl[w][(rb * 16 + lg * 4 + r) * 72 + f * 16 + lr] = (short)f2bf(sc[rb][f][r]);

    s16x8 pf[2][2];
    #pragma unroll
    for (int rb = 0; rb < 2; ++rb)
      #pragma unroll
      for (int kk = 0; kk < 2; ++kk)
        pf[rb][kk] = *reinterpret_cast<const s16x8*>(&Pl[w][(rb * 16 + lr) * 72 + kk * 32 + lg * 8]);

    #pragma unroll
    for (int f = 0; f < 4; ++f) {
      #pragma unroll
      for (int kk = 0; kk < 2; ++kk) {
        s16x8 vf = *reinterpret_cast<const s16x8*>(&Vs[(f * 16 + lr) * 72 + kk * 32 + lg * 8]);
        #pragma unroll
        for (int rb = 0; rb < 2; ++rb)
          acco[rb][f] = __builtin_amdgcn_mfma_f32_16x16x32_bf16(pf[rb][kk], vf, acco[rb][f], 0, 0, 0);
      }
    }

    __syncthreads();              // everyone done reading tile tt
    if (tt < 9) {
      #pragma unroll
      for (int p = 0; p < 2; ++p) {
        *reinterpret_cast<s16x8*>(&Ks[rowk * 72 + colk + p * 8]) = kreg[p];
        *reinterpret_cast<s16x8*>(&Vs[rowk * 72 + colk + p * 8]) = vreg[p];
      }
    }
  }

  // normalize + write concat output (bf16)
  #pragma unroll
  for (int rb = 0; rb < 2; ++rb) {
    #pragma unroll
    for (int r = 0; r < 4; ++r) {
      int s = q0 + w * 32 + rb * 16 + lg * 4 + r;
      if (s < SEQ) {
        float inv = 1.0f / lsum[rb][r];
        #pragma unroll
        for (int f = 0; f < 4; ++f) {
          int d = f * 16 + lr;
          cat[((size_t)b * SEQ + s) * EMB + h * HD + d] = (short)f2bf(acco[rb][f][r] * inv);
        }
      }
    }
  }
}

extern "C" void kernel_launch(void* const* d_in, const int* in_sizes, int n_in,
                              void* d_out, int out_size, void* d_ws, size_t ws_size,
                              hipStream_t stream) {
  const float* x  = (const float*)d_in[0];
  const float* wq = (const float*)d_in[1];
  const float* wk = (const float*)d_in[2];
  const float* wv = (const float*)d_in[3];
  const float* wp = (const float*)d_in[4];
  const float* bp = (const float*)d_in[5];
  float* out = (float*)d_out;

  char* ws = (char*)d_ws;
  short* xb   = (short*)ws;                         // 28,360,704 B (reused as cat)
  short* wqkv = (short*)(ws + 28360704);            //  3,538,944 B
  short* wpb  = (short*)(ws + 31899648);            //  1,179,648 B
  short* qkb  = (short*)(ws + 33079296);            // 56,721,408 B (Q,K planes)
  short* vtb  = (short*)(ws + 89800704);            // 31,457,280 B (V^T [bh][d][640])
  short* cat  = xb;                                 // x dead after QKV GEMM

  cvt_x<<<6924, 256, 0, stream>>>(x, xb, 1772544);
  cvt_w<<<1152, 256, 0, stream>>>(wq, wk, wv, wp, wqkv, wpb);
  gemm_bt<0><<<145 * 18, 256, 0, stream>>>(xb, wqkv, qkb, vtb, nullptr, nullptr, TOK, 18);
  attn<<<1920, 256, 0, stream>>>(qkb, vtb, cat);
  gemm_bt<1><<<145 * 6, 256, 0, stream>>>(cat, wpb, nullptr, nullptr, out, bp, TOK, 6);
}